// Round 1
// baseline (380.356 us; speedup 1.0000x reference)
//
#include <hip/hip_runtime.h>

typedef _Float16 f16;
typedef f16 half8 __attribute__((ext_vector_type(8)));
typedef float f32x4 __attribute__((ext_vector_type(4)));

#define MFMA16(a, b, c) __builtin_amdgcn_mfma_f32_16x16x32_f16((a), (b), (c), 0, 0, 0)

static constexpr int B = 8, C = 256, CI = 128, N = 6272, M = 1568;

// f16-element offsets into workspace (total ~80 MB)
static constexpr size_t oXT = 0;                         // [B][N][C]   x transposed, f16
static constexpr size_t oQ  = (size_t)B * N * C;         // [B][N][CI]  theta
static constexpr size_t oPF = oQ  + (size_t)B * N * CI;  // [B][N][CI]  phi full-res
static constexpr size_t oGF = oPF + (size_t)B * N * CI;  // [B][N][CI]  g full-res
static constexpr size_t oPP = oGF + (size_t)B * N * CI;  // [B][M][CI]  phi pooled (K)
static constexpr size_t oGT = oPP + (size_t)B * M * CI;  // [B][CI][M]  g pooled, transposed (V)
static constexpr size_t oY  = oGT + (size_t)B * M * CI;  // [B][N][CI]  attention out
static constexpr size_t oW  = oY  + (size_t)B * N * CI;  // 4*32768 f16 weights: theta|phi|g|W

// ---------------- weight cast fp32 -> f16 ----------------
__global__ void k_prep(const float* tw, const float* pw, const float* gw,
                       const float* Ww, f16* dst) {
    int i = blockIdx.x * 256 + threadIdx.x;   // 0..131071
    int s = i >> 15, j = i & 32767;
    float v;
    if (s == 0) v = tw[j];
    else if (s == 1) v = pw[j];
    else if (s == 2) v = gw[j];
    else v = Ww[j];
    dst[i] = (f16)v;
}

// ---------------- x[b][c][n] fp32 -> xT[b][n][c] f16 ----------------
__global__ void k_trans(const float* x, f16* xT) {
    __shared__ float tile[32][33];
    int b = blockIdx.z, nt = blockIdx.x, ct = blockIdx.y;
    int tx = threadIdx.x, ty = threadIdx.y;
#pragma unroll
    for (int i = 0; i < 4; i++) {
        int c = ct * 32 + ty + i * 8;
        tile[ty + i * 8][tx] = x[(size_t)(b * C + c) * N + nt * 32 + tx];
    }
    __syncthreads();
#pragma unroll
    for (int i = 0; i < 4; i++) {
        int n = nt * 32 + ty + i * 8;
        xT[(size_t)(b * N + n) * C + ct * 32 + tx] = (f16)tile[tx][ty + i * 8];
    }
}

// ---------------- projection GEMM: out[b][n][ci] = xT[b][n][:] . w16[ci][:] + bias ----------------
__global__ __launch_bounds__(256) void k_proj(const f16* __restrict__ xT,
                                              const f16* __restrict__ w16,
                                              const float* __restrict__ bias,
                                              f16* __restrict__ out) {
    __shared__ f16 xs[128 * 72];   // [128 n][64 k] pad 8
    __shared__ f16 ws[128 * 72];   // [128 ci][64 k] pad 8
    int b = blockIdx.z, n0 = blockIdx.x * 128;
    int tid = threadIdx.x, w = tid >> 6, lane = tid & 63, ln = lane & 15, quad = lane >> 4;
    f32x4 acc[2][8];
#pragma unroll
    for (int rb = 0; rb < 2; rb++)
#pragma unroll
        for (int cb = 0; cb < 8; cb++) acc[rb][cb] = (f32x4){0.f, 0.f, 0.f, 0.f};

    for (int kc = 0; kc < 4; kc++) {
#pragma unroll
        for (int i = 0; i < 4; i++) {
            int qq = tid + i * 256;              // 0..1023
            int row = qq >> 3, coff = (qq & 7) * 8;
            *(int4*)&xs[row * 72 + coff] =
                *(const int4*)&xT[(size_t)(b * N + n0 + row) * C + kc * 64 + coff];
            *(int4*)&ws[row * 72 + coff] =
                *(const int4*)&w16[(size_t)row * C + kc * 64 + coff];
        }
        __syncthreads();
#pragma unroll
        for (int ks = 0; ks < 2; ks++) {
            half8 a0 = *(const half8*)&xs[(w * 32 + ln) * 72 + ks * 32 + quad * 8];
            half8 a1 = *(const half8*)&xs[(w * 32 + 16 + ln) * 72 + ks * 32 + quad * 8];
#pragma unroll
            for (int cb = 0; cb < 8; cb++) {
                half8 bf = *(const half8*)&ws[(cb * 16 + ln) * 72 + ks * 32 + quad * 8];
                acc[0][cb] = MFMA16(a0, bf, acc[0][cb]);
                acc[1][cb] = MFMA16(a1, bf, acc[1][cb]);
            }
        }
        __syncthreads();
    }
#pragma unroll
    for (int cb = 0; cb < 8; cb++) {
        float bv = bias[cb * 16 + ln];
#pragma unroll
        for (int rb = 0; rb < 2; rb++) {
#pragma unroll
            for (int r = 0; r < 4; r++) {
                int n = n0 + w * 32 + rb * 16 + quad * 4 + r;
                out[(size_t)(b * N + n) * CI + cb * 16 + ln] = (f16)(acc[rb][cb][r] + bv);
            }
        }
    }
}

// ---------------- 2x2 spatial maxpool; K as [m][ci], V as [ci][m] ----------------
__global__ void k_pool(const f16* __restrict__ phiF, const f16* __restrict__ gF,
                       f16* __restrict__ phiP, f16* __restrict__ gPT) {
    int b = blockIdx.y, m = blockIdx.x, ci = threadIdx.x;
    int t = m / 196, r = m % 196, hp = r / 14, wp = r % 14;
    int n0 = t * 784 + hp * 56 + wp * 2;   // (t, 2hp, 2wp)
    size_t base = (size_t)(b * N) * CI + ci;
    float p0 = (float)phiF[base + (size_t)n0 * CI];
    float p1 = (float)phiF[base + (size_t)(n0 + 1) * CI];
    float p2 = (float)phiF[base + (size_t)(n0 + 28) * CI];
    float p3 = (float)phiF[base + (size_t)(n0 + 29) * CI];
    phiP[(size_t)(b * M + m) * CI + ci] = (f16)fmaxf(fmaxf(p0, p1), fmaxf(p2, p3));
    float g0 = (float)gF[base + (size_t)n0 * CI];
    float g1 = (float)gF[base + (size_t)(n0 + 1) * CI];
    float g2 = (float)gF[base + (size_t)(n0 + 28) * CI];
    float g3 = (float)gF[base + (size_t)(n0 + 29) * CI];
    gPT[(size_t)(b * CI + ci) * M + m] = (f16)fmaxf(fmaxf(g0, g1), fmaxf(g2, g3));
}

// ---------------- flash attention: y[b][n][ci] ----------------
__global__ __launch_bounds__(256) void k_attn(const f16* __restrict__ q,
                                              const f16* __restrict__ k,
                                              const f16* __restrict__ v,
                                              f16* __restrict__ y) {
    __shared__ f16 Qs[64 * 136];    // [64 q][128 d] pad 8
    __shared__ f16 Ks[32 * 136];    // [32 m][128 d] pad 8
    __shared__ f16 Vs[128 * 40];    // [128 ci][32 m] pad 8
    __shared__ f16 Ps[4 * 16 * 40]; // per-wave [16 q][32 m] pad 8
    int b = blockIdx.y, n0 = blockIdx.x * 64;
    int tid = threadIdx.x, w = tid >> 6, lane = tid & 63, ln = lane & 15, quad = lane >> 4;

#pragma unroll
    for (int i = 0; i < 4; i++) {
        int qq = tid + i * 256; int row = qq >> 4, coff = (qq & 15) * 8;
        *(int4*)&Qs[row * 136 + coff] =
            *(const int4*)&q[(size_t)(b * N + n0 + row) * CI + coff];
    }
    f32x4 O[8];
#pragma unroll
    for (int cb = 0; cb < 8; cb++) O[cb] = (f32x4){0.f, 0.f, 0.f, 0.f};
    float mi[4] = {-1e30f, -1e30f, -1e30f, -1e30f};
    float li[4] = {0.f, 0.f, 0.f, 0.f};
    __syncthreads();

    for (int mc = 0; mc < 49; mc++) {
#pragma unroll
        for (int i = 0; i < 2; i++) {
            int qq = tid + i * 256;            // 0..511
            int row = qq >> 4, coff = (qq & 15) * 8;
            *(int4*)&Ks[row * 136 + coff] =
                *(const int4*)&k[(size_t)(b * M + mc * 32 + row) * CI + coff];
            int vrow = qq >> 2, moff = (qq & 3) * 8;
            *(int4*)&Vs[vrow * 40 + moff] =
                *(const int4*)&v[(size_t)(b * CI + vrow) * M + mc * 32 + moff];
        }
        __syncthreads();

        f32x4 S0 = (f32x4){0.f, 0.f, 0.f, 0.f}, S1 = (f32x4){0.f, 0.f, 0.f, 0.f};
#pragma unroll
        for (int ks = 0; ks < 4; ks++) {
            half8 aq = *(const half8*)&Qs[(w * 16 + ln) * 136 + ks * 32 + quad * 8];
            half8 b0 = *(const half8*)&Ks[ln * 136 + ks * 32 + quad * 8];
            half8 b1 = *(const half8*)&Ks[(16 + ln) * 136 + ks * 32 + quad * 8];
            S0 = MFMA16(aq, b0, S0);
            S1 = MFMA16(aq, b1, S1);
        }
        // online softmax per q-row (row = quad*4 + r); cols live across 16 lanes of the quad
#pragma unroll
        for (int r = 0; r < 4; r++) {
            float vmx = fmaxf(S0[r], S1[r]);
            vmx = fmaxf(vmx, __shfl_xor(vmx, 1));
            vmx = fmaxf(vmx, __shfl_xor(vmx, 2));
            vmx = fmaxf(vmx, __shfl_xor(vmx, 4));
            vmx = fmaxf(vmx, __shfl_xor(vmx, 8));
            float mnew = fmaxf(mi[r], vmx);
            float alpha = __expf(mi[r] - mnew);
            float p0 = __expf(S0[r] - mnew);
            float p1 = __expf(S1[r] - mnew);
            float rs = p0 + p1;
            rs += __shfl_xor(rs, 1);
            rs += __shfl_xor(rs, 2);
            rs += __shfl_xor(rs, 4);
            rs += __shfl_xor(rs, 8);
            li[r] = li[r] * alpha + rs;
            mi[r] = mnew;
            Ps[w * 640 + (quad * 4 + r) * 40 + ln] = (f16)p0;
            Ps[w * 640 + (quad * 4 + r) * 40 + 16 + ln] = (f16)p1;
#pragma unroll
            for (int cb = 0; cb < 8; cb++) O[cb][r] *= alpha;
        }
        // PV: P (A-layout via LDS round-trip), V from [ci][m]
        half8 ap = *(const half8*)&Ps[w * 640 + ln * 40 + quad * 8];
#pragma unroll
        for (int cb = 0; cb < 8; cb++) {
            half8 bv = *(const half8*)&Vs[(cb * 16 + ln) * 40 + quad * 8];
            O[cb] = MFMA16(ap, bv, O[cb]);
        }
        __syncthreads();
    }
#pragma unroll
    for (int cb = 0; cb < 8; cb++) {
#pragma unroll
        for (int r = 0; r < 4; r++) {
            int n = n0 + w * 16 + quad * 4 + r;
            y[(size_t)(b * N + n) * CI + cb * 16 + ln] = (f16)(O[cb][r] / li[r]);
        }
    }
}

// ---------------- final: out[b][c][n] = W.y + Wb + x ----------------
__global__ __launch_bounds__(256) void k_final(const f16* __restrict__ y,
                                               const f16* __restrict__ Ww,
                                               const float* __restrict__ Wb,
                                               const float* __restrict__ x,
                                               float* __restrict__ out) {
    __shared__ f16 ys[64 * 136];    // [64 n][128 ci] pad 8
    __shared__ f16 Ws[128 * 136];   // [128 c][128 ci] pad 8
    int b = blockIdx.z, ch = blockIdx.y, n0 = blockIdx.x * 64;
    int tid = threadIdx.x, w = tid >> 6, lane = tid & 63, ln = lane & 15, quad = lane >> 4;
#pragma unroll
    for (int i = 0; i < 4; i++) {
        int qq = tid + i * 256; int row = qq >> 4, coff = (qq & 15) * 8;
        *(int4*)&ys[row * 136 + coff] =
            *(const int4*)&y[(size_t)(b * N + n0 + row) * CI + coff];
    }
#pragma unroll
    for (int i = 0; i < 8; i++) {
        int qq = tid + i * 256; int row = qq >> 4, coff = (qq & 15) * 8;
        *(int4*)&Ws[row * 136 + coff] =
            *(const int4*)&Ww[(size_t)(ch * 128 + row) * CI + coff];
    }
    __syncthreads();
    f32x4 acc[2][4];
#pragma unroll
    for (int rb = 0; rb < 2; rb++)
#pragma unroll
        for (int nb = 0; nb < 4; nb++) acc[rb][nb] = (f32x4){0.f, 0.f, 0.f, 0.f};
#pragma unroll
    for (int ks = 0; ks < 4; ks++) {
        half8 a0 = *(const half8*)&Ws[(w * 32 + ln) * 136 + ks * 32 + quad * 8];
        half8 a1 = *(const half8*)&Ws[(w * 32 + 16 + ln) * 136 + ks * 32 + quad * 8];
#pragma unroll
        for (int nb = 0; nb < 4; nb++) {
            half8 bf = *(const half8*)&ys[(nb * 16 + ln) * 136 + ks * 32 + quad * 8];
            acc[0][nb] = MFMA16(a0, bf, acc[0][nb]);
            acc[1][nb] = MFMA16(a1, bf, acc[1][nb]);
        }
    }
#pragma unroll
    for (int rb = 0; rb < 2; rb++) {
        int cbase = ch * 128 + w * 32 + rb * 16 + quad * 4;
#pragma unroll
        for (int nb = 0; nb < 4; nb++) {
#pragma unroll
            for (int r = 0; r < 4; r++) {
                int c = cbase + r;
                size_t addr = (size_t)(b * C + c) * N + n0 + nb * 16 + ln;
                out[addr] = acc[rb][nb][r] + Wb[c] + x[addr];
            }
        }
    }
}

extern "C" void kernel_launch(void* const* d_in, const int* in_sizes, int n_in,
                              void* d_out, int out_size, void* d_ws, size_t ws_size,
                              hipStream_t stream) {
    const float* x  = (const float*)d_in[0];
    const float* gw = (const float*)d_in[1];
    const float* gb = (const float*)d_in[2];
    const float* tw = (const float*)d_in[3];
    const float* tb = (const float*)d_in[4];
    const float* pw = (const float*)d_in[5];
    const float* pb = (const float*)d_in[6];
    const float* Ww = (const float*)d_in[7];
    const float* Wb = (const float*)d_in[8];
    float* out = (float*)d_out;
    f16* ws = (f16*)d_ws;

    f16* xT   = ws + oXT;
    f16* Q    = ws + oQ;
    f16* phiF = ws + oPF;
    f16* gF   = ws + oGF;
    f16* phiP = ws + oPP;
    f16* gPT  = ws + oGT;
    f16* Y    = ws + oY;
    f16* w16  = ws + oW;

    k_prep<<<512, 256, 0, stream>>>(tw, pw, gw, Ww, w16);
    k_trans<<<dim3(196, 8, 8), dim3(32, 8), 0, stream>>>(x, xT);
    k_proj<<<dim3(49, 1, 8), 256, 0, stream>>>(xT, w16,         tb, Q);
    k_proj<<<dim3(49, 1, 8), 256, 0, stream>>>(xT, w16 + 32768, pb, phiF);
    k_proj<<<dim3(49, 1, 8), 256, 0, stream>>>(xT, w16 + 65536, gb, gF);
    k_pool<<<dim3(1568, 8), 128, 0, stream>>>(phiF, gF, phiP, gPT);
    k_attn<<<dim3(98, 8), 256, 0, stream>>>(Q, phiP, gPT, Y);
    k_final<<<dim3(98, 2, 8), 256, 0, stream>>>(Y, w16 + 98304, Wb, x, out);
    (void)in_sizes; (void)n_in; (void)out_size; (void)ws_size;
}

// Round 2
// 269.137 us; speedup vs baseline: 1.4132x; 1.4132x over previous
//
#include <hip/hip_runtime.h>

typedef _Float16 f16;
typedef f16 half8 __attribute__((ext_vector_type(8)));
typedef float f32x4 __attribute__((ext_vector_type(4)));

#define MFMA16(a, b, c) __builtin_amdgcn_mfma_f32_16x16x32_f16((a), (b), (c), 0, 0, 0)

static constexpr int B = 8, C = 256, CI = 128, N = 6272, M = 1568, MP = 1600;

// f16-element offsets into workspace (~71 MB). Y aliases phiF (consumed by k_pool).
static constexpr size_t oXT = 0;                         // [B][N][C]   x transposed, f16
static constexpr size_t oQ  = (size_t)B * N * C;         // [B][N][CI]  theta (log2e folded at attn load)
static constexpr size_t oPF = oQ  + (size_t)B * N * CI;  // [B][N][CI]  phi full-res; later Y
static constexpr size_t oGF = oPF + (size_t)B * N * CI;  // [B][N][CI]  g full-res
static constexpr size_t oPP = oGF + (size_t)B * N * CI;  // [B][MP][CI] phi pooled (K), pad zeroed
static constexpr size_t oGT = oPP + (size_t)B * MP * CI; // [B][CI][MP] g pooled transposed (V), pad zeroed
static constexpr size_t oW  = oGT + (size_t)B * MP * CI; // 4*32768 f16 weights: theta|phi|g|W

static __device__ __forceinline__ half8 hmax8(half8 a, half8 b) {
    half8 r;
#pragma unroll
    for (int j = 0; j < 8; j++) r[j] = a[j] > b[j] ? a[j] : b[j];
    return r;
}

// max across the 16 consecutive lanes of a DPP row (our 16-lane "quad" groups)
static __device__ __forceinline__ float rowmax16(float x) {
    int t;
    t = __builtin_amdgcn_update_dpp(__float_as_int(x), __float_as_int(x), 0x121, 0xF, 0xF, false);
    x = fmaxf(x, __int_as_float(t));
    t = __builtin_amdgcn_update_dpp(__float_as_int(x), __float_as_int(x), 0x122, 0xF, 0xF, false);
    x = fmaxf(x, __int_as_float(t));
    t = __builtin_amdgcn_update_dpp(__float_as_int(x), __float_as_int(x), 0x124, 0xF, 0xF, false);
    x = fmaxf(x, __int_as_float(t));
    t = __builtin_amdgcn_update_dpp(__float_as_int(x), __float_as_int(x), 0x128, 0xF, 0xF, false);
    x = fmaxf(x, __int_as_float(t));
    return x;
}

// ---------------- weight cast fp32 -> f16 ----------------
__global__ void k_prep(const float* tw, const float* pw, const float* gw,
                       const float* Ww, f16* dst) {
    int i = blockIdx.x * 256 + threadIdx.x;   // 0..131071
    int s = i >> 15, j = i & 32767;
    float v;
    if (s == 0) v = tw[j];
    else if (s == 1) v = pw[j];
    else if (s == 2) v = gw[j];
    else v = Ww[j];
    dst[i] = (f16)v;
}

// ---------------- x[b][c][n] fp32 -> xT[b][n][c] f16 ----------------
__global__ void k_trans(const float* x, f16* xT) {
    __shared__ float tile[32][33];
    int b = blockIdx.z, nt = blockIdx.x, ct = blockIdx.y;
    int tx = threadIdx.x, ty = threadIdx.y;
#pragma unroll
    for (int i = 0; i < 4; i++) {
        int c = ct * 32 + ty + i * 8;
        tile[ty + i * 8][tx] = x[(size_t)(b * C + c) * N + nt * 32 + tx];
    }
    __syncthreads();
#pragma unroll
    for (int i = 0; i < 4; i++) {
        int n = nt * 32 + ty + i * 8;
        xT[(size_t)(b * N + n) * C + ct * 32 + tx] = (f16)tile[tx][ty + i * 8];
    }
}

// ---------------- projection GEMM: out[b][n][ci] = xT[b][n][:] . w16[ci][:] + bias ----------------
__global__ __launch_bounds__(256) void k_proj(const f16* __restrict__ xT,
                                              const f16* __restrict__ w16,
                                              const float* __restrict__ bias,
                                              f16* __restrict__ out) {
    __shared__ f16 xs[128 * 72];   // [128 n][64 k] pad 8
    __shared__ f16 ws[128 * 72];   // [128 ci][64 k] pad 8
    int b = blockIdx.z, n0 = blockIdx.x * 128;
    int tid = threadIdx.x, w = tid >> 6, lane = tid & 63, ln = lane & 15, quad = lane >> 4;
    f32x4 acc[2][8];
#pragma unroll
    for (int rb = 0; rb < 2; rb++)
#pragma unroll
        for (int cb = 0; cb < 8; cb++) acc[rb][cb] = (f32x4){0.f, 0.f, 0.f, 0.f};

    for (int kc = 0; kc < 4; kc++) {
#pragma unroll
        for (int i = 0; i < 4; i++) {
            int qq = tid + i * 256;              // 0..1023
            int row = qq >> 3, coff = (qq & 7) * 8;
            *(int4*)&xs[row * 72 + coff] =
                *(const int4*)&xT[(size_t)(b * N + n0 + row) * C + kc * 64 + coff];
            *(int4*)&ws[row * 72 + coff] =
                *(const int4*)&w16[(size_t)row * C + kc * 64 + coff];
        }
        __syncthreads();
#pragma unroll
        for (int ks = 0; ks < 2; ks++) {
            half8 a0 = *(const half8*)&xs[(w * 32 + ln) * 72 + ks * 32 + quad * 8];
            half8 a1 = *(const half8*)&xs[(w * 32 + 16 + ln) * 72 + ks * 32 + quad * 8];
#pragma unroll
            for (int cb = 0; cb < 8; cb++) {
                half8 bf = *(const half8*)&ws[(cb * 16 + ln) * 72 + ks * 32 + quad * 8];
                acc[0][cb] = MFMA16(a0, bf, acc[0][cb]);
                acc[1][cb] = MFMA16(a1, bf, acc[1][cb]);
            }
        }
        __syncthreads();
    }
#pragma unroll
    for (int cb = 0; cb < 8; cb++) {
        float bv = bias[cb * 16 + ln];
#pragma unroll
        for (int rb = 0; rb < 2; rb++) {
#pragma unroll
            for (int r = 0; r < 4; r++) {
                int n = n0 + w * 32 + rb * 16 + quad * 4 + r;
                out[(size_t)(b * N + n) * CI + cb * 16 + ln] = (f16)(acc[rb][cb][r] + bv);
            }
        }
    }
}

// ---------------- 2x2 spatial maxpool; K as [m][ci], V as [ci][m] (coalesced via LDS transpose) ----
__global__ __launch_bounds__(256) void k_pool(const f16* __restrict__ phiF, const f16* __restrict__ gF,
                                              f16* __restrict__ phiP, f16* __restrict__ gPT) {
    __shared__ f16 gt[128 * 72];   // [128 ci][64 m] pad 8
    int b = blockIdx.y, mt = blockIdx.x;   // mt 0..24 over MP=1600
    int tid = threadIdx.x;
#pragma unroll
    for (int i = 0; i < 4; i++) {
        int qq = tid + i * 256;            // 0..1023
        int ml = qq >> 4, coff = (qq & 15) * 8;
        int m = mt * 64 + ml;
        half8 pv, gv;
        if (m < M) {
            int t = m / 196, rr = m % 196, hp = rr / 14, wp = rr % 14;
            int nb = t * 784 + hp * 56 + wp * 2;
            size_t base = ((size_t)(b * N) + nb) * CI + coff;
            half8 p0 = *(const half8*)&phiF[base];
            half8 p1 = *(const half8*)&phiF[base + CI];
            half8 p2 = *(const half8*)&phiF[base + 28 * CI];
            half8 p3 = *(const half8*)&phiF[base + 29 * CI];
            pv = hmax8(hmax8(p0, p1), hmax8(p2, p3));
            half8 g0 = *(const half8*)&gF[base];
            half8 g1 = *(const half8*)&gF[base + CI];
            half8 g2 = *(const half8*)&gF[base + 28 * CI];
            half8 g3 = *(const half8*)&gF[base + 29 * CI];
            gv = hmax8(hmax8(g0, g1), hmax8(g2, g3));
        } else {
#pragma unroll
            for (int j = 0; j < 8; j++) { pv[j] = (f16)0.f; gv[j] = (f16)0.f; }
        }
        *(half8*)&phiP[((size_t)b * MP + m) * CI + coff] = pv;
#pragma unroll
        for (int j = 0; j < 8; j++) gt[(coff + j) * 72 + ml] = gv[j];
    }
    __syncthreads();
#pragma unroll
    for (int i = 0; i < 4; i++) {
        int qq = tid + i * 256;
        int ci = qq >> 3, moff = (qq & 7) * 8;
        *(int4*)&gPT[((size_t)(b * CI) + ci) * MP + mt * 64 + moff] = *(const int4*)&gt[ci * 72 + moff];
    }
}

// ---------------- flash attention: y[b][n][ci]; Q regs, m-chunk 64, ones-MFMA rowsum, DPP max ----
__global__ __launch_bounds__(256, 2) void k_attn(const f16* __restrict__ q,
                                                 const f16* __restrict__ kk,
                                                 const f16* __restrict__ v,
                                                 f16* __restrict__ y) {
    __shared__ f16 Ks[64 * 136];     // [64 m][128 d] pad 8 (stride 272B, 16B-aligned, 2-way banks)
    __shared__ f16 Vs[128 * 72];     // [128 ci][64 m] pad 8
    __shared__ f16 Ps[4 * 32 * 72];  // per-wave [32 q][64 m] pad 8
    int b = blockIdx.y, n0 = blockIdx.x * 128;
    int tid = threadIdx.x, w = tid >> 6, lane = tid & 63, ln = lane & 15, quad = lane >> 4;
    int wq = n0 + w * 32;
    f16* Pw = &Ps[w * 32 * 72];

    // Q fragments in registers, pre-scaled by log2(e) so softmax is pure exp2
    half8 qf[2][4];
#pragma unroll
    for (int qt = 0; qt < 2; qt++)
#pragma unroll
        for (int ks = 0; ks < 4; ks++) {
            qf[qt][ks] = *(const half8*)&q[(size_t)(b * N + wq + qt * 16 + ln) * CI + ks * 32 + quad * 8];
#pragma unroll
            for (int j = 0; j < 8; j++) qf[qt][ks][j] *= (f16)1.4426950408889634f;
        }

    f32x4 O[2][8], Osum[2];
#pragma unroll
    for (int qt = 0; qt < 2; qt++) {
        Osum[qt] = (f32x4){0.f, 0.f, 0.f, 0.f};
#pragma unroll
        for (int cb = 0; cb < 8; cb++) O[qt][cb] = (f32x4){0.f, 0.f, 0.f, 0.f};
    }
    float mi[2][4] = {{-1e30f, -1e30f, -1e30f, -1e30f}, {-1e30f, -1e30f, -1e30f, -1e30f}};

    for (int mc = 0; mc < 25; mc++) {
        // ---- stage K (16KB) + V (16KB) ----
#pragma unroll
        for (int i = 0; i < 4; i++) {
            int qq = tid + i * 256;
            int kr = qq >> 4, kc = (qq & 15) * 8;
            *(int4*)&Ks[kr * 136 + kc] = *(const int4*)&kk[((size_t)b * MP + mc * 64 + kr) * CI + kc];
            int vr = qq >> 3, vc = (qq & 7) * 8;
            *(int4*)&Vs[vr * 72 + vc] = *(const int4*)&v[((size_t)(b * CI) + vr) * MP + mc * 64 + vc];
        }
        __syncthreads();

        // ---- QK^T: 32 MFMA, each K fragment feeds both q-tiles ----
        f32x4 S[2][4];
#pragma unroll
        for (int mt = 0; mt < 4; mt++) {
            f32x4 s0 = (f32x4){0.f, 0.f, 0.f, 0.f}, s1 = (f32x4){0.f, 0.f, 0.f, 0.f};
#pragma unroll
            for (int ks = 0; ks < 4; ks++) {
                half8 kb = *(const half8*)&Ks[(mt * 16 + ln) * 136 + ks * 32 + quad * 8];
                s0 = MFMA16(qf[0][ks], kb, s0);
                s1 = MFMA16(qf[1][ks], kb, s1);
            }
            S[0][mt] = s0; S[1][mt] = s1;
        }

        // ---- online softmax (log2 domain): DPP row-max, no sum shuffles ----
#pragma unroll
        for (int qt = 0; qt < 2; qt++)
#pragma unroll
            for (int r = 0; r < 4; r++) {
                float vm = fmaxf(fmaxf(S[qt][0][r], S[qt][1][r]), fmaxf(S[qt][2][r], S[qt][3][r]));
                vm = rowmax16(vm);
                float mnew = fmaxf(mi[qt][r], vm);
                float alpha = __builtin_amdgcn_exp2f(mi[qt][r] - mnew);
                mi[qt][r] = mnew;
#pragma unroll
                for (int mt = 0; mt < 4; mt++) {
                    float p = __builtin_amdgcn_exp2f(S[qt][mt][r] - mnew);
                    Pw[(qt * 16 + quad * 4 + r) * 72 + mt * 16 + ln] = (f16)p;
                }
#pragma unroll
                for (int cb = 0; cb < 8; cb++) O[qt][cb][r] *= alpha;
                Osum[qt][r] *= alpha;
            }

        // ---- PV + ones-column rowsum: 36 MFMA, each V fragment feeds both q-tiles ----
#pragma unroll
        for (int ks = 0; ks < 2; ks++) {
            half8 a0 = *(const half8*)&Pw[ln * 72 + ks * 32 + quad * 8];
            half8 a1 = *(const half8*)&Pw[(16 + ln) * 72 + ks * 32 + quad * 8];
            f16 ov = (mc * 64 + ks * 32 < M) ? (f16)1.0f : (f16)0.0f;  // mask pad cols (1568 % 32 == 0)
            half8 on;
#pragma unroll
            for (int j = 0; j < 8; j++) on[j] = ov;
#pragma unroll
            for (int cb = 0; cb < 8; cb++) {
                half8 bv = *(const half8*)&Vs[(cb * 16 + ln) * 72 + ks * 32 + quad * 8];
                O[0][cb] = MFMA16(a0, bv, O[0][cb]);
                O[1][cb] = MFMA16(a1, bv, O[1][cb]);
            }
            Osum[0] = MFMA16(a0, on, Osum[0]);
            Osum[1] = MFMA16(a1, on, Osum[1]);
        }
        __syncthreads();
    }

#pragma unroll
    for (int qt = 0; qt < 2; qt++)
#pragma unroll
        for (int cb = 0; cb < 8; cb++)
#pragma unroll
            for (int r = 0; r < 4; r++) {
                int n = wq + qt * 16 + quad * 4 + r;
                y[(size_t)(b * N + n) * CI + cb * 16 + ln] = (f16)(O[qt][cb][r] / Osum[qt][r]);
            }
}

// ---------------- final: out[b][c][n] = W.y + Wb + x ----------------
__global__ __launch_bounds__(256) void k_final(const f16* __restrict__ y,
                                               const f16* __restrict__ Ww,
                                               const float* __restrict__ Wb,
                                               const float* __restrict__ x,
                                               float* __restrict__ out) {
    __shared__ f16 ys[64 * 136];    // [64 n][128 ci] pad 8
    __shared__ f16 Ws[128 * 136];   // [128 c][128 ci] pad 8
    int b = blockIdx.z, ch = blockIdx.y, n0 = blockIdx.x * 64;
    int tid = threadIdx.x, w = tid >> 6, lane = tid & 63, ln = lane & 15, quad = lane >> 4;
#pragma unroll
    for (int i = 0; i < 4; i++) {
        int qq = tid + i * 256; int row = qq >> 4, coff = (qq & 15) * 8;
        *(int4*)&ys[row * 136 + coff] =
            *(const int4*)&y[(size_t)(b * N + n0 + row) * CI + coff];
    }
#pragma unroll
    for (int i = 0; i < 8; i++) {
        int qq = tid + i * 256; int row = qq >> 4, coff = (qq & 15) * 8;
        *(int4*)&Ws[row * 136 + coff] =
            *(const int4*)&Ww[(size_t)(ch * 128 + row) * CI + coff];
    }
    __syncthreads();
    f32x4 acc[2][4];
#pragma unroll
    for (int rb = 0; rb < 2; rb++)
#pragma unroll
        for (int nb = 0; nb < 4; nb++) acc[rb][nb] = (f32x4){0.f, 0.f, 0.f, 0.f};
#pragma unroll
    for (int ks = 0; ks < 4; ks++) {
        half8 a0 = *(const half8*)&Ws[(w * 32 + ln) * 136 + ks * 32 + quad * 8];
        half8 a1 = *(const half8*)&Ws[(w * 32 + 16 + ln) * 136 + ks * 32 + quad * 8];
#pragma unroll
        for (int nb = 0; nb < 4; nb++) {
            half8 bf = *(const half8*)&ys[(nb * 16 + ln) * 136 + ks * 32 + quad * 8];
            acc[0][nb] = MFMA16(a0, bf, acc[0][nb]);
            acc[1][nb] = MFMA16(a1, bf, acc[1][nb]);
        }
    }
#pragma unroll
    for (int rb = 0; rb < 2; rb++) {
        int cbase = ch * 128 + w * 32 + rb * 16 + quad * 4;
#pragma unroll
        for (int nb = 0; nb < 4; nb++) {
#pragma unroll
            for (int r = 0; r < 4; r++) {
                int c = cbase + r;
                size_t addr = (size_t)(b * C + c) * N + n0 + nb * 16 + ln;
                out[addr] = acc[rb][nb][r] + Wb[c] + x[addr];
            }
        }
    }
}

extern "C" void kernel_launch(void* const* d_in, const int* in_sizes, int n_in,
                              void* d_out, int out_size, void* d_ws, size_t ws_size,
                              hipStream_t stream) {
    const float* x  = (const float*)d_in[0];
    const float* gw = (const float*)d_in[1];
    const float* gb = (const float*)d_in[2];
    const float* tw = (const float*)d_in[3];
    const float* tb = (const float*)d_in[4];
    const float* pw = (const float*)d_in[5];
    const float* pb = (const float*)d_in[6];
    const float* Ww = (const float*)d_in[7];
    const float* Wb = (const float*)d_in[8];
    float* out = (float*)d_out;
    f16* ws = (f16*)d_ws;

    f16* xT   = ws + oXT;
    f16* Q    = ws + oQ;
    f16* phiF = ws + oPF;
    f16* gF   = ws + oGF;
    f16* phiP = ws + oPP;
    f16* gPT  = ws + oGT;
    f16* Y    = ws + oPF;   // alias: phiF dead after k_pool
    f16* w16  = ws + oW;

    k_prep<<<512, 256, 0, stream>>>(tw, pw, gw, Ww, w16);
    k_trans<<<dim3(196, 8, 8), dim3(32, 8), 0, stream>>>(x, xT);
    k_proj<<<dim3(49, 1, 8), 256, 0, stream>>>(xT, w16,         tb, Q);
    k_proj<<<dim3(49, 1, 8), 256, 0, stream>>>(xT, w16 + 32768, pb, phiF);
    k_proj<<<dim3(49, 1, 8), 256, 0, stream>>>(xT, w16 + 65536, gb, gF);
    k_pool<<<dim3(25, 8), 256, 0, stream>>>(phiF, gF, phiP, gPT);
    k_attn<<<dim3(49, 8), 256, 0, stream>>>(Q, phiP, gPT, Y);
    k_final<<<dim3(98, 2, 8), 256, 0, stream>>>(Y, w16 + 98304, Wb, x, out);
    (void)in_sizes; (void)n_in; (void)out_size; (void)ws_size;
}